// Round 2
// baseline (400.901 us; speedup 1.0000x reference)
//
#include <hip/hip_runtime.h>
#include <math.h>

// DiscriminativeLoss, 2-kernel no-cooperative structure.
// embeddings (8,16,512,512) f32, instance_masks (8,512,512) i32 in [0,33)
// out: 4 f32 [total, var, dist, reg]
//
// K1: per-wave LDS histogram (ds_add_f32) -> per-block flush to gsum (global atomics).
//     Streams mask+emb once, fully coalesced (16 B/lane).
// K2: re-reads mask+emb (L3-warm from K1), weighted hinge vs swizzled LDS means,
//     per-block atomic into vsum, then LAST-BLOCK ticket finalizes all losses
//     (no 3rd kernel, no cooperative launch, no co-residency assumption).
//
// ws layout (cache-line separated):
//   gsum   @ 0      : B*32*17 floats (cols 0..15 sums, col 16 count), segs 1..32
//   vsum   @ 20480  : B floats
//   ticket @ 24576  : 1 uint
// memset covers 0..28672.

#define B 8
#define E 16
#define HW (512*512)
#define HW4 (HW/4)
#define BLK 256
#define XBLK 128
#define ITERS 2                 // XBLK*BLK*ITERS == HW4
#define NBLOCKS (XBLK*B)

#define VSUM_OFF   20480
#define TICKET_OFF 24576

__device__ __forceinline__ float atomAddF(float* p, float v) {
  return unsafeAtomicAdd(p, v);
}

// ---------------- K1: segment sums+counts via per-wave LDS histogram ----------------
__global__ __launch_bounds__(BLK, 4) void hist_kernel(
    const float* __restrict__ emb, const int* __restrict__ mask,
    float* __restrict__ gsum /*[B][32][17]*/) {
  __shared__ float hist[4][33][17];   // per-wave (9.0 KB); stride 17 odd -> ids spread banks
  const int b  = blockIdx.y;
  const int t  = threadIdx.x;
  const int wv = t >> 6;

  for (int i = t; i < 4 * 33 * 17; i += BLK) ((float*)hist)[i] = 0.f;
  __syncthreads();

  const int4*   __restrict__ maskv = (const int4*)(mask + (size_t)b * HW);
  const float4* __restrict__ embv  = (const float4*)(emb + (size_t)b * E * HW);
  const int gbase = blockIdx.x * (BLK * ITERS) + t;

#pragma unroll
  for (int it = 0; it < ITERS; ++it) {
    const int g = gbase + it * BLK;
    const int4 id = maskv[g];
    float4 x[E];
#pragma unroll
    for (int e = 0; e < E; ++e) x[e] = embv[(size_t)e * HW4 + g];

#pragma unroll
    for (int e = 0; e < E; ++e) {
      atomicAdd(&hist[wv][id.x][e], x[e].x);
      atomicAdd(&hist[wv][id.y][e], x[e].y);
      atomicAdd(&hist[wv][id.z][e], x[e].z);
      atomicAdd(&hist[wv][id.w][e], x[e].w);
    }
    atomicAdd(&hist[wv][id.x][16], 1.f);
    atomicAdd(&hist[wv][id.y][16], 1.f);
    atomicAdd(&hist[wv][id.z][16], 1.f);
    atomicAdd(&hist[wv][id.w][16], 1.f);
  }
  __syncthreads();

  // flush per-block partials (id 0 = background, discarded)
  for (int i = t; i < 32 * 17; i += BLK) {
    const int id = i / 17 + 1;
    const int e  = i % 17;
    const float s = hist[0][id][e] + hist[1][id][e]
                  + hist[2][id][e] + hist[3][id][e];
    atomAddF(&gsum[((size_t)b * 32 + (id - 1)) * 17 + e], s);
  }
}

// ---------------- K2: weighted hinge + last-block finalize ----------------
__global__ __launch_bounds__(BLK, 4) void hinge_kernel(
    const float* __restrict__ emb, const int* __restrict__ mask,
    const float* __restrict__ gsum, float* __restrict__ vsum,
    unsigned* __restrict__ ticket, float* __restrict__ out) {
  // Swizzle: logical chunk j of row k at physical slot (j+k+(k>>2))&3 (verified)
  __shared__ __align__(16) float mean4[33][4][4];
  __shared__ float winv[33];
  __shared__ float wred[4];
  __shared__ unsigned tkt;
  // last-block finalize scratch
  __shared__ __align__(16) float c_mean[B][32][E];  // 16 KB
  __shared__ float c_cnt[B][32];
  __shared__ float c_rb[B], c_db[B], c_pb[B], c_nb[B];

  const int b = blockIdx.y;
  const int t = threadIdx.x;
  const int wv = t >> 6;

  // means -> LDS (gsum complete: K1 finished at kernel boundary)
  for (int i = t; i < 33 * 16; i += BLK) {
    const int k = i >> 4, e = i & 15;
    float m = 0.f;
    if (k >= 1) {
      const float cnt = gsum[((size_t)b * 32 + (k - 1)) * 17 + 16];
      const float cc  = cnt > 1.f ? cnt : 1.f;
      m = gsum[((size_t)b * 32 + (k - 1)) * 17 + e] / cc;
    }
    const int j = e >> 2;
    mean4[k][(j + k + (k >> 2)) & 3][e & 3] = m;
  }
  if (t < 33) {
    float w = 0.f;
    if (t >= 1) {
      const float cnt = gsum[((size_t)b * 32 + (t - 1)) * 17 + 16];
      w = cnt > 0.5f ? 1.f / cnt : 0.f;
    }
    winv[t] = w;
  }
  __syncthreads();

  const int4*   __restrict__ maskv = (const int4*)(mask + (size_t)b * HW);
  const float4* __restrict__ embv  = (const float4*)(emb + (size_t)b * E * HW);
  const int gbase = blockIdx.x * (BLK * ITERS) + t;
  float vacc = 0.f;

#pragma unroll
  for (int it = 0; it < ITERS; ++it) {
    const int g = gbase + it * BLK;
    const int4 id = maskv[g];
    float4 x[E];
#pragma unroll
    for (int e = 0; e < E; ++e) x[e] = embv[(size_t)e * HW4 + g];

    const int sx = id.x + (id.x >> 2);
    const int sy = id.y + (id.y >> 2);
    const int sz = id.z + (id.z >> 2);
    const int sw = id.w + (id.w >> 2);

    float d0 = 0.f, d1 = 0.f, d2 = 0.f, d3 = 0.f;
#pragma unroll
    for (int j = 0; j < 4; ++j) {
      const float4 m0 = *(const float4*)&mean4[id.x][(j + sx) & 3][0];
      const float4 m1 = *(const float4*)&mean4[id.y][(j + sy) & 3][0];
      const float4 m2 = *(const float4*)&mean4[id.z][(j + sz) & 3][0];
      const float4 m3 = *(const float4*)&mean4[id.w][(j + sw) & 3][0];
      const float4 a0 = x[4 * j + 0], a1 = x[4 * j + 1];
      const float4 a2 = x[4 * j + 2], a3 = x[4 * j + 3];
      float u;
      u = a0.x - m0.x; d0 += u * u;  u = a1.x - m0.y; d0 += u * u;
      u = a2.x - m0.z; d0 += u * u;  u = a3.x - m0.w; d0 += u * u;
      u = a0.y - m1.x; d1 += u * u;  u = a1.y - m1.y; d1 += u * u;
      u = a2.y - m1.z; d1 += u * u;  u = a3.y - m1.w; d1 += u * u;
      u = a0.z - m2.x; d2 += u * u;  u = a1.z - m2.y; d2 += u * u;
      u = a2.z - m2.z; d2 += u * u;  u = a3.z - m2.w; d2 += u * u;
      u = a0.w - m3.x; d3 += u * u;  u = a1.w - m3.y; d3 += u * u;
      u = a2.w - m3.z; d3 += u * u;  u = a3.w - m3.w; d3 += u * u;
    }
    float hh;   // winv[0]=0 kills background
    hh = fmaxf(sqrtf(d0) - 0.5f, 0.f); vacc += hh * hh * winv[id.x];
    hh = fmaxf(sqrtf(d1) - 0.5f, 0.f); vacc += hh * hh * winv[id.y];
    hh = fmaxf(sqrtf(d2) - 0.5f, 0.f); vacc += hh * hh * winv[id.z];
    hh = fmaxf(sqrtf(d3) - 0.5f, 0.f); vacc += hh * hh * winv[id.w];
  }

  // block reduce -> one global atomic
#pragma unroll
  for (int off = 32; off >= 1; off >>= 1) vacc += __shfl_down(vacc, off, 64);
  if ((t & 63) == 0) wred[wv] = vacc;
  __syncthreads();

  if (t == 0) {
    atomAddF(&vsum[b], wred[0] + wred[1] + wred[2] + wred[3]);
    __threadfence();                      // vsum add ordered before ticket
    tkt = atomicAdd(ticket, 1u);
  }
  __syncthreads();
  if (tkt != NBLOCKS - 1) return;

  // ---------------- last block: finalize ----------------
  __threadfence();
  {
    const int bb = t >> 5, k = t & 31;    // 256 threads = B*32 exactly
    const float c  = gsum[((size_t)bb * 32 + k) * 17 + 16];
    const float cc = c > 1.f ? c : 1.f;
    c_cnt[bb][k] = c;
#pragma unroll
    for (int e = 0; e < E; ++e)
      c_mean[bb][k][e] = gsum[((size_t)bb * 32 + k) * 17 + e] / cc;
  }
  if (t < B) { c_rb[t] = 0.f; c_db[t] = 0.f; c_pb[t] = 0.f; c_nb[t] = 0.f; }
  __syncthreads();

  {
    const int bb = t >> 5, k = t & 31;
    const float c = c_cnt[bb][k];
    if (c > 0.5f) {
      atomicAdd(&c_nb[bb], 1.f);
      float sq = 0.f;
#pragma unroll
      for (int e = 0; e < E; ++e) { const float m = c_mean[bb][k][e]; sq += m * m; }
      atomicAdd(&c_rb[bb], sq > 0.f ? sqrtf(sq) : 0.f);
    }
  }

  // pair loss: register accumulation per (wave, bb)
  for (int bb = 0; bb < B; ++bb) {
    float dacc = 0.f, pacc = 0.f;
    for (int p = t; p < 32 * 32; p += BLK) {
      const int i = p >> 5, j = p & 31;
      if (i < j && c_cnt[bb][i] > 0.5f && c_cnt[bb][j] > 0.5f) {
        pacc += 1.f;
        const float4* mi = (const float4*)&c_mean[bb][i][0];
        const float4* mj = (const float4*)&c_mean[bb][j][0];
        float sq = 0.f;
#pragma unroll
        for (int q = 0; q < 4; ++q) {
          const float4 a = mi[q], c4 = mj[q];
          float u;
          u = a.x - c4.x; sq += u * u;  u = a.y - c4.y; sq += u * u;
          u = a.z - c4.z; sq += u * u;  u = a.w - c4.w; sq += u * u;
        }
        const float dn = sq > 0.f ? sqrtf(sq) : 0.f;
        const float hh = 3.0f - dn;     // 2*DELTA_D - d
        if (hh > 0.f) dacc += hh * hh;
      }
    }
#pragma unroll
    for (int off = 32; off >= 1; off >>= 1) {
      dacc += __shfl_down(dacc, off, 64);
      pacc += __shfl_down(pacc, off, 64);
    }
    if ((t & 63) == 0) {
      atomicAdd(&c_db[bb], dacc);
      atomicAdd(&c_pb[bb], pacc);
    }
  }
  __syncthreads();

  if (t == 0) {
    float sv = 0.f, sd = 0.f, sr = 0.f, svalid = 0.f;
    for (int bb = 0; bb < B; ++bb) {
      // atomic load: coherent view of other blocks' device-scope atomic adds
      const float vb = __hip_atomic_load(&vsum[bb], __ATOMIC_RELAXED,
                                         __HIP_MEMORY_SCOPE_AGENT);
      const float ni  = c_nb[bb];
      const float nim = ni > 1.f ? ni : 1.f;
      const float var_b = vb / nim;
      const float reg_b = c_rb[bb] / nim;
      const float npm   = c_pb[bb] > 1.f ? c_pb[bb] : 1.f;
      const float dist_b = (ni > 1.f) ? (c_db[bb] / npm) : 0.f;
      const float valid  = ni > 0.f ? 1.f : 0.f;
      sv += var_b * valid;
      sd += dist_b * valid;
      sr += reg_b * valid;
      svalid += valid;
    }
    const float vs = svalid > 1.f ? svalid : 1.f;
    const float var = sv / vs, dist = sd / vs, reg = sr / vs;
    out[0] = var + dist + 0.001f * reg;
    out[1] = var;
    out[2] = dist;
    out[3] = reg;
  }
}

extern "C" void kernel_launch(void* const* d_in, const int* in_sizes, int n_in,
                              void* d_out, int out_size, void* d_ws, size_t ws_size,
                              hipStream_t stream) {
  const float* emb  = (const float*)d_in[0];
  const int*   mask = (const int*)d_in[1];
  float* out = (float*)d_out;

  float*    gsum   = (float*)d_ws;
  float*    vsum   = (float*)((char*)d_ws + VSUM_OFF);
  unsigned* ticket = (unsigned*)((char*)d_ws + TICKET_OFF);

  hipMemsetAsync(d_ws, 0, 28672, stream);

  hist_kernel <<<dim3(XBLK, B), BLK, 0, stream>>>(emb, mask, gsum);
  hinge_kernel<<<dim3(XBLK, B), BLK, 0, stream>>>(emb, mask, gsum, vsum, ticket, out);
}

// Round 3
// 276.791 us; speedup vs baseline: 1.4484x; 1.4484x over previous
//
#include <hip/hip_runtime.h>
#include <math.h>

// DiscriminativeLoss, 2-kernel structure.
// embeddings (8,16,512,512) f32, instance_masks (8,512,512) i32 in [0,33)
// out: 4 f32 [total, var, dist, reg]
//
// K1 (mfma_hist): segment sums via one-hot MFMA 16x16x32 bf16 (2 MFMAs cover
//     segments 1..32), ALL 64 lanes carry B-data, loads 128B-coalesced per
//     channel plane. Counts via tiny mask-only LDS histogram. NO per-pixel
//     channel atomics (round-2 hist died on launch_bounds-induced VGPR cap +
//     serialized loads: VGPR=52 < the 64 needed, VALUBusy 0.4%).
// K2 (hinge): re-reads mask+emb (L3-warm), weighted hinge vs swizzled LDS
//     means, last-block ticket finalizes. launch_bounds WITHOUT min-waves so
//     the 16 in-flight float4 loads get real registers.
//
// ws layout: gsum @0 (B*32*17 f32; cols 0..15 sums, col 16 count, segs 1..32),
//            vsum @20480 (B f32), ticket @24576 (1 u32). memset 0..28672.

#define B 8
#define E 16
#define HW (512*512)
#define HW4 (HW/4)
#define BLK 256
#define XBLK 128
#define PPB (HW / XBLK)        // 2048 px per block
#define PPW (PPB / 4)          // 512 px per wave
#define NTILE (PPW / 32)       // 16 tiles of 32 px per wave
#define ITERS 2                // K2: XBLK*BLK*ITERS == HW4
#define NBLOCKS (XBLK * B)

#define VSUM_OFF   20480
#define TICKET_OFF 24576

typedef __attribute__((ext_vector_type(8))) short short8;
typedef __attribute__((ext_vector_type(4))) float floatx4;

__device__ __forceinline__ float atomAddF(float* p, float v) {
  return unsafeAtomicAdd(p, v);
}

// pack trunc-bf16(a) | trunc-bf16(b)<<16 in ONE v_perm_b32 (verified in prior session)
__device__ __forceinline__ unsigned pack_bf(float a, float b) {
  return __builtin_amdgcn_perm(__float_as_uint(b), __float_as_uint(a), 0x07060302u);
}

// ---------------- K1: segment sums via one-hot MFMA, counts via LDS hist ----------------
__global__ __launch_bounds__(BLK) void mfma_hist_kernel(
    const float* __restrict__ emb, const int* __restrict__ mask,
    float* __restrict__ gsum /*[B][32][17]*/) {
  __shared__ int4 mstage[PPB / 4];                // 8 KB: block's 2048 mask ids
  __shared__ float cnt4[4][33];                   // per-wave count histogram
  __shared__ __align__(16) float lred[4][32][17]; // cross-wave reduce (8.7 KB)

  const int b    = blockIdx.y;
  const int t    = threadIdx.x;
  const int lane = t & 63;
  const int wv   = __builtin_amdgcn_readfirstlane(t >> 6);
  const int r    = lane & 15;     // A: segment row (id r+1 / r+17). B: channel col.
  const int g    = lane >> 4;     // k-group: pixels g*8 .. g*8+7 within tile

  for (int i = t; i < 4 * 33; i += BLK) ((float*)cnt4)[i] = 0.f;

  // ---- stage mask + count histogram (8 LDS atomics/thread total) ----
  const int blockbase = blockIdx.x * PPB;
  {
    const int4* __restrict__ mg = (const int4*)(mask + (size_t)b * HW + blockbase);
    const int4 ma = mg[t];
    const int4 mb = mg[BLK + t];
    mstage[t]       = ma;
    mstage[BLK + t] = mb;
    __syncthreads();   // cnt4 zeroed before atomics; mstage visible later anyway
    atomicAdd(&cnt4[wv][ma.x], 1.f);
    atomicAdd(&cnt4[wv][ma.y], 1.f);
    atomicAdd(&cnt4[wv][ma.z], 1.f);
    atomicAdd(&cnt4[wv][ma.w], 1.f);
    atomicAdd(&cnt4[wv][mb.x], 1.f);
    atomicAdd(&cnt4[wv][mb.y], 1.f);
    atomicAdd(&cnt4[wv][mb.z], 1.f);
    atomicAdd(&cnt4[wv][mb.w], 1.f);
  }
  __syncthreads();

  // per-lane plane pointer: channel r, wave's pixel run, k-group offset
  const float* __restrict__ pl =
      emb + ((size_t)b * E + r) * HW + blockbase + wv * PPW + g * 8;
  const int mbase = wv * (PPW / 4) + g * 2;   // int4 index into mstage

  floatx4 acc_lo, acc_hi;
#pragma unroll
  for (int q = 0; q < 4; ++q) { acc_lo[q] = 0.f; acc_hi[q] = 0.f; }

  const int rid_lo = r + 1, rid_hi = r + 17;

#pragma unroll 4
  for (int tl = 0; tl < NTILE; ++tl) {
    // B: 8 pixels of channel r (2 x float4, 128B-coalesced across the 4 k-groups)
    const float4 f0 = ((const float4*)(pl + tl * 32))[0];
    const float4 f1 = ((const float4*)(pl + tl * 32))[1];

    // A: 8 mask ids for this k-group (broadcast LDS reads: 16 lanes same addr)
    const int4 A0 = mstage[mbase + tl * 8];
    const int4 A1 = mstage[mbase + tl * 8 + 1];

    short8 af_lo, af_hi;
    af_lo[0] = (A0.x == rid_lo) ? (short)0x3F80 : (short)0;
    af_lo[1] = (A0.y == rid_lo) ? (short)0x3F80 : (short)0;
    af_lo[2] = (A0.z == rid_lo) ? (short)0x3F80 : (short)0;
    af_lo[3] = (A0.w == rid_lo) ? (short)0x3F80 : (short)0;
    af_lo[4] = (A1.x == rid_lo) ? (short)0x3F80 : (short)0;
    af_lo[5] = (A1.y == rid_lo) ? (short)0x3F80 : (short)0;
    af_lo[6] = (A1.z == rid_lo) ? (short)0x3F80 : (short)0;
    af_lo[7] = (A1.w == rid_lo) ? (short)0x3F80 : (short)0;
    af_hi[0] = (A0.x == rid_hi) ? (short)0x3F80 : (short)0;
    af_hi[1] = (A0.y == rid_hi) ? (short)0x3F80 : (short)0;
    af_hi[2] = (A0.z == rid_hi) ? (short)0x3F80 : (short)0;
    af_hi[3] = (A0.w == rid_hi) ? (short)0x3F80 : (short)0;
    af_hi[4] = (A1.x == rid_hi) ? (short)0x3F80 : (short)0;
    af_hi[5] = (A1.y == rid_hi) ? (short)0x3F80 : (short)0;
    af_hi[6] = (A1.z == rid_hi) ? (short)0x3F80 : (short)0;
    af_hi[7] = (A1.w == rid_hi) ? (short)0x3F80 : (short)0;

    union { uint4 u4; short8 s; } cv;
    cv.u4.x = pack_bf(f0.x, f0.y);
    cv.u4.y = pack_bf(f0.z, f0.w);
    cv.u4.z = pack_bf(f1.x, f1.y);
    cv.u4.w = pack_bf(f1.z, f1.w);

    acc_lo = __builtin_amdgcn_mfma_f32_16x16x32_bf16(af_lo, cv.s, acc_lo, 0, 0, 0);
    acc_hi = __builtin_amdgcn_mfma_f32_16x16x32_bf16(af_hi, cv.s, acc_hi, 0, 0, 0);
  }

  // C/D (m89-verified): col = lane&15 (channel), row = (lane>>4)*4 + reg (segment idx)
#pragma unroll
  for (int q = 0; q < 4; ++q) {
    lred[wv][g * 4 + q][r]      = acc_lo[q];
    lred[wv][16 + g * 4 + q][r] = acc_hi[q];
  }
  __syncthreads();

  // flush per-block partials: 544 global atomics/block
  for (int i = t; i < 32 * 17; i += BLK) {
    const int s = i / 17;        // segment index -> id s+1
    const int c = i % 17;
    float v;
    if (c < 16) {
      v = lred[0][s][c] + lred[1][s][c] + lred[2][s][c] + lred[3][s][c];
    } else {
      v = cnt4[0][s + 1] + cnt4[1][s + 1] + cnt4[2][s + 1] + cnt4[3][s + 1];
    }
    atomAddF(&gsum[((size_t)b * 32 + s) * 17 + c], v);
  }
}

// ---------------- K2: weighted hinge + last-block finalize ----------------
__global__ __launch_bounds__(BLK) void hinge_kernel(
    const float* __restrict__ emb, const int* __restrict__ mask,
    const float* __restrict__ gsum, float* __restrict__ vsum,
    unsigned* __restrict__ ticket, float* __restrict__ out) {
  // Swizzle: logical chunk j of row k at physical slot (j+k+(k>>2))&3 (verified)
  __shared__ __align__(16) float mean4[33][4][4];
  __shared__ float winv[33];
  __shared__ float wred[4];
  __shared__ unsigned tkt;
  // last-block finalize scratch
  __shared__ __align__(16) float c_mean[B][32][E];  // 16 KB
  __shared__ float c_cnt[B][32];
  __shared__ float c_rb[B], c_db[B], c_pb[B], c_nb[B];

  const int b = blockIdx.y;
  const int t = threadIdx.x;
  const int wv = t >> 6;

  for (int i = t; i < 33 * 16; i += BLK) {
    const int k = i >> 4, e = i & 15;
    float m = 0.f;
    if (k >= 1) {
      const float cnt = gsum[((size_t)b * 32 + (k - 1)) * 17 + 16];
      const float cc  = cnt > 1.f ? cnt : 1.f;
      m = gsum[((size_t)b * 32 + (k - 1)) * 17 + e] / cc;
    }
    const int j = e >> 2;
    mean4[k][(j + k + (k >> 2)) & 3][e & 3] = m;
  }
  if (t < 33) {
    float w = 0.f;
    if (t >= 1) {
      const float cnt = gsum[((size_t)b * 32 + (t - 1)) * 17 + 16];
      w = cnt > 0.5f ? 1.f / cnt : 0.f;
    }
    winv[t] = w;
  }
  __syncthreads();

  const int4*   __restrict__ maskv = (const int4*)(mask + (size_t)b * HW);
  const float4* __restrict__ embv  = (const float4*)(emb + (size_t)b * E * HW);
  const int gbase = blockIdx.x * (BLK * ITERS) + t;
  float vacc = 0.f;

#pragma unroll
  for (int it = 0; it < ITERS; ++it) {
    const int gi = gbase + it * BLK;
    const int4 id = maskv[gi];
    float4 x[E];
#pragma unroll
    for (int e = 0; e < E; ++e) x[e] = embv[(size_t)e * HW4 + gi];

    const int sx = id.x + (id.x >> 2);
    const int sy = id.y + (id.y >> 2);
    const int sz = id.z + (id.z >> 2);
    const int sw = id.w + (id.w >> 2);

    float d0 = 0.f, d1 = 0.f, d2 = 0.f, d3 = 0.f;
#pragma unroll
    for (int j = 0; j < 4; ++j) {
      const float4 m0 = *(const float4*)&mean4[id.x][(j + sx) & 3][0];
      const float4 m1 = *(const float4*)&mean4[id.y][(j + sy) & 3][0];
      const float4 m2 = *(const float4*)&mean4[id.z][(j + sz) & 3][0];
      const float4 m3 = *(const float4*)&mean4[id.w][(j + sw) & 3][0];
      const float4 a0 = x[4 * j + 0], a1 = x[4 * j + 1];
      const float4 a2 = x[4 * j + 2], a3 = x[4 * j + 3];
      float u;
      u = a0.x - m0.x; d0 += u * u;  u = a1.x - m0.y; d0 += u * u;
      u = a2.x - m0.z; d0 += u * u;  u = a3.x - m0.w; d0 += u * u;
      u = a0.y - m1.x; d1 += u * u;  u = a1.y - m1.y; d1 += u * u;
      u = a2.y - m1.z; d1 += u * u;  u = a3.y - m1.w; d1 += u * u;
      u = a0.z - m2.x; d2 += u * u;  u = a1.z - m2.y; d2 += u * u;
      u = a2.z - m2.z; d2 += u * u;  u = a3.z - m2.w; d2 += u * u;
      u = a0.w - m3.x; d3 += u * u;  u = a1.w - m3.y; d3 += u * u;
      u = a2.w - m3.z; d3 += u * u;  u = a3.w - m3.w; d3 += u * u;
    }
    float hh;   // winv[0]=0 kills background
    hh = fmaxf(sqrtf(d0) - 0.5f, 0.f); vacc += hh * hh * winv[id.x];
    hh = fmaxf(sqrtf(d1) - 0.5f, 0.f); vacc += hh * hh * winv[id.y];
    hh = fmaxf(sqrtf(d2) - 0.5f, 0.f); vacc += hh * hh * winv[id.z];
    hh = fmaxf(sqrtf(d3) - 0.5f, 0.f); vacc += hh * hh * winv[id.w];
  }

#pragma unroll
  for (int off = 32; off >= 1; off >>= 1) vacc += __shfl_down(vacc, off, 64);
  if ((t & 63) == 0) wred[wv] = vacc;
  __syncthreads();

  if (t == 0) {
    atomAddF(&vsum[b], wred[0] + wred[1] + wred[2] + wred[3]);
    __threadfence();                      // vsum add ordered before ticket
    tkt = atomicAdd(ticket, 1u);
  }
  __syncthreads();
  if (tkt != NBLOCKS - 1) return;

  // ---------------- last block: finalize ----------------
  __threadfence();
  {
    const int bb = t >> 5, k = t & 31;    // 256 threads = B*32 exactly
    const float c  = gsum[((size_t)bb * 32 + k) * 17 + 16];
    const float cc = c > 1.f ? c : 1.f;
    c_cnt[bb][k] = c;
#pragma unroll
    for (int e = 0; e < E; ++e)
      c_mean[bb][k][e] = gsum[((size_t)bb * 32 + k) * 17 + e] / cc;
  }
  if (t < B) { c_rb[t] = 0.f; c_db[t] = 0.f; c_pb[t] = 0.f; c_nb[t] = 0.f; }
  __syncthreads();

  {
    const int bb = t >> 5, k = t & 31;
    const float c = c_cnt[bb][k];
    if (c > 0.5f) {
      atomicAdd(&c_nb[bb], 1.f);
      float sq = 0.f;
#pragma unroll
      for (int e = 0; e < E; ++e) { const float m = c_mean[bb][k][e]; sq += m * m; }
      atomicAdd(&c_rb[bb], sq > 0.f ? sqrtf(sq) : 0.f);
    }
  }

  for (int bb = 0; bb < B; ++bb) {
    float dacc = 0.f, pacc = 0.f;
    for (int p = t; p < 32 * 32; p += BLK) {
      const int i = p >> 5, j = p & 31;
      if (i < j && c_cnt[bb][i] > 0.5f && c_cnt[bb][j] > 0.5f) {
        pacc += 1.f;
        const float4* mi = (const float4*)&c_mean[bb][i][0];
        const float4* mj = (const float4*)&c_mean[bb][j][0];
        float sq = 0.f;
#pragma unroll
        for (int q = 0; q < 4; ++q) {
          const float4 a = mi[q], c4 = mj[q];
          float u;
          u = a.x - c4.x; sq += u * u;  u = a.y - c4.y; sq += u * u;
          u = a.z - c4.z; sq += u * u;  u = a.w - c4.w; sq += u * u;
        }
        const float dn = sq > 0.f ? sqrtf(sq) : 0.f;
        const float hh = 3.0f - dn;     // 2*DELTA_D - d
        if (hh > 0.f) dacc += hh * hh;
      }
    }
#pragma unroll
    for (int off = 32; off >= 1; off >>= 1) {
      dacc += __shfl_down(dacc, off, 64);
      pacc += __shfl_down(pacc, off, 64);
    }
    if ((t & 63) == 0) {
      atomicAdd(&c_db[bb], dacc);
      atomicAdd(&c_pb[bb], pacc);
    }
  }
  __syncthreads();

  if (t == 0) {
    float sv = 0.f, sd = 0.f, sr = 0.f, svalid = 0.f;
    for (int bb = 0; bb < B; ++bb) {
      const float vb = __hip_atomic_load(&vsum[bb], __ATOMIC_RELAXED,
                                         __HIP_MEMORY_SCOPE_AGENT);
      const float ni  = c_nb[bb];
      const float nim = ni > 1.f ? ni : 1.f;
      const float var_b = vb / nim;
      const float reg_b = c_rb[bb] / nim;
      const float npm   = c_pb[bb] > 1.f ? c_pb[bb] : 1.f;
      const float dist_b = (ni > 1.f) ? (c_db[bb] / npm) : 0.f;
      const float valid  = ni > 0.f ? 1.f : 0.f;
      sv += var_b * valid;
      sd += dist_b * valid;
      sr += reg_b * valid;
      svalid += valid;
    }
    const float vs = svalid > 1.f ? svalid : 1.f;
    const float var = sv / vs, dist = sd / vs, reg = sr / vs;
    out[0] = var + dist + 0.001f * reg;
    out[1] = var;
    out[2] = dist;
    out[3] = reg;
  }
}

extern "C" void kernel_launch(void* const* d_in, const int* in_sizes, int n_in,
                              void* d_out, int out_size, void* d_ws, size_t ws_size,
                              hipStream_t stream) {
  const float* emb  = (const float*)d_in[0];
  const int*   mask = (const int*)d_in[1];
  float* out = (float*)d_out;

  float*    gsum   = (float*)d_ws;
  float*    vsum   = (float*)((char*)d_ws + VSUM_OFF);
  unsigned* ticket = (unsigned*)((char*)d_ws + TICKET_OFF);

  hipMemsetAsync(d_ws, 0, 28672, stream);

  mfma_hist_kernel<<<dim3(XBLK, B), BLK, 0, stream>>>(emb, mask, gsum);
  hinge_kernel    <<<dim3(XBLK, B), BLK, 0, stream>>>(emb, mask, gsum, vsum, ticket, out);
}